// Round 12
// baseline (436.094 us; speedup 1.0000x reference)
//
#include <hip/hip_runtime.h>

#define TT 512
#define MM 16      // batch rows per block; grid 256 = 1 block/CU (min-work shape)

typedef _Float16 f16_t;
typedef f16_t f16x8 __attribute__((ext_vector_type(8)));
typedef float  f32x4 __attribute__((ext_vector_type(4)));
typedef unsigned uintx4 __attribute__((ext_vector_type(4)));

#define MFMA16(A, B, C) __builtin_amdgcn_mfma_f32_16x16x32_f16((A), (B), (C), 0, 0, 0)

__device__ __forceinline__ float fr(float x) { return __builtin_amdgcn_rcpf(x); }

#if __has_builtin(__builtin_amdgcn_exp2f)
__device__ __forceinline__ float ex2(float x) { return __builtin_amdgcn_exp2f(x); }
#define EXS 1.44269504f
#else
__device__ __forceinline__ float ex2(float x) { return __expf(x); }
#define EXS 1.0f
#endif

#if __has_builtin(__builtin_amdgcn_cvt_pkrtz)
__device__ __forceinline__ unsigned pk2(float a, float b) {
    auto p = __builtin_amdgcn_cvt_pkrtz(a, b);   // __fp16 ext_vector(2)
    return __builtin_bit_cast(unsigned, p);
}
#else
__device__ __forceinline__ unsigned pk2(float a, float b) {
    unsigned short ha = __builtin_bit_cast(unsigned short, (f16_t)a);
    unsigned short hb = __builtin_bit_cast(unsigned short, (f16_t)b);
    return (unsigned)ha | ((unsigned)hb << 16);
}
#endif

// barrier: LDS-only wait (x prefetch stays in flight across barriers).
__device__ __forceinline__ void bar() {
    asm volatile("s_waitcnt lgkmcnt(0)" ::: "memory");
    __builtin_amdgcn_s_barrier();
    asm volatile("" ::: "memory");
}

// LSTM cell, 7 trans (5 ex2 + 2 rcp), NaN-safe (identical math to R10/R11):
//   c' = (c*u + oa*(C-1)) * rcp(oa*u);  oa = 1+e^-f^, u = (1+e^-i^)(C+1), C = e^2g^
//   h  = (E-1) * rcp((1+D)(E+1)),  E = 2^min(2*EXS*c', 30)
// Biases pre-folded & scaled: bq = { -EXS*bi, -EXS*bf, 2*EXS*bg, -EXS*bo }.
__device__ __forceinline__ float cellEW(float pi, float pf, float pg, float po,
                                        float4 bq, float& c) {
    float A = ex2(fmaf(pf, -EXS, bq.y));
    float B = ex2(fmaf(pi, -EXS, bq.x));
    float C = ex2(fmaf(pg, 2.f * EXS, bq.z));
    float oa = 1.f + A;
    float u  = (1.f + B) * (C + 1.f);
    float cn = fmaf(c, u, oa * (C - 1.f)) * fr(oa * u);
    c = cn;
    float D = ex2(fmaf(po, -EXS, bq.w));
    float E = ex2(fminf(2.f * EXS * cn, 30.f));
    return (E - 1.f) * fr((1.f + D) * (E + 1.f));
}

__device__ __forceinline__ f16x8 cvt8(const float* p) {
    f16x8 r;
#pragma unroll
    for (int e = 0; e < 8; ++e) r[e] = (f16_t)p[e];
    return r;
}

// SWAPPED-OPERAND MFMA (verified R10/R11):
//   A (arg0) = weight tile:  lane l -> gcol = tile + l%16, k = (l/16)*8+e
//   B (arg1) = h:            lane l -> row  = l%16,        k = (l/16)*8+e
//   D:                       lane l -> row  = l%16, gcol-in-tile = (l/16)*4+q
// h-plane [16 rows][64 hcols] f16, byte(row,hcol) = (row*128 + hcol*2) ^ ((row&7)<<4).
//
// R12 anti-phase schedule (2 lgkm-only barriers/step; SIMD i hosts L2 wave i + L1 wave i+4):
//   H1: L1: ds_read h1(t) + MFMA gates1(t+1) -> a1   | L2: EW(a2 = gates2(t-1)) -> h2(t-1)
//   H2: L1: EW(a1) -> h1(t+1)[p^1]                   | L2: ds_read h2, MFMA gates2(t) -> a2
// h1 double-buffered; h2 single-buffered (H1-write / H2-read, barrier-separated).

__global__ __launch_bounds__(512, 2) void lstm_v12(
    const float* __restrict__ x,
    const float* __restrict__ w_ih0, const float* __restrict__ w_hh0,
    const float* __restrict__ b_ih0, const float* __restrict__ b_hh0,
    const float* __restrict__ w_ih1, const float* __restrict__ w_hh1,
    const float* __restrict__ b_ih1, const float* __restrict__ b_hh1,
    const float* __restrict__ fc1_w, const float* __restrict__ fc1_b,
    const float* __restrict__ fc2_w, const float* __restrict__ fc2_b,
    float* __restrict__ out)
{
    __shared__ __align__(16) unsigned h1p[2][512];   // h1 planes (double buffer)
    __shared__ __align__(16) unsigned h2p[512];      // h2 plane (single)
    __shared__ __align__(16) float sH[MM * 68];
    __shared__ float sY[MM * 34];

    const int tid = threadIdx.x;
    const int l   = tid & 63;
    const int wv  = tid >> 6;
    const int rbase = blockIdx.x * MM;

    const int lc = l & 15;
    const int lq = l >> 4;
    const bool isL1 = (wv >= 4);
    const int wsub = wv & 3;
    const int hc0  = wsub * 16 + lq * 4;
    const int swz  = (lc & 7) << 4;

    const int rdo0 = (lc * 128 + 0 * 64 + lq * 16) ^ swz;
    const int rdo1 = (lc * 128 + 1 * 64 + lq * 16) ^ swz;
    const int wro  = (lc * 128 + hc0 * 2) ^ swz;
    const unsigned xmask = (lq == 0) ? 0xFFFFFFFFu : 0u;

    // ---------------- prologue: weight A-fragments -> registers ----------------
    f16x8 wA[4][2];   // L1: w_hh0 ; L2: w_ih1
    f16x8 wB[4][2];   // L2 only: w_hh1
    f16x8 wx[4];      // L1 only: w_ih0 (k=0..3)
    float4 bq[4];
#pragma unroll
    for (int g = 0; g < 4; ++g) {
        const int grow = (g * 64 + wsub * 16 + lc) * 64 + lq * 8;
        if (isL1) {
            wA[g][0] = cvt8(w_hh0 + grow);
            wA[g][1] = cvt8(w_hh0 + grow + 32);
            const int ga = (g * 64 + wsub * 16 + lc) * 4;
#pragma unroll
            for (int e = 0; e < 8; ++e)
                wx[g][e] = (e < 4 && lq == 0) ? (f16_t)w_ih0[ga + e] : (f16_t)0.f;
        } else {
            wA[g][0] = cvt8(w_ih1 + grow);
            wA[g][1] = cvt8(w_ih1 + grow + 32);
            wB[g][0] = cvt8(w_hh1 + grow);
            wB[g][1] = cvt8(w_hh1 + grow + 32);
        }
    }
#pragma unroll
    for (int q = 0; q < 4; ++q) {
        const int hc = hc0 + q;
        float b[4];
#pragma unroll
        for (int g = 0; g < 4; ++g) {
            const int ga = g * 64 + hc;
            b[g] = isL1 ? (b_ih0[ga] + b_hh0[ga]) : (b_ih1[ga] + b_hh1[ga]);
        }
        bq[q] = make_float4(-EXS * b[0], -EXS * b[1], 2.f * EXS * b[2], -EXS * b[3]);
    }

    float c_st[4] = {0.f, 0.f, 0.f, 0.f};
    const f32x4 z4 = {0.f, 0.f, 0.f, 0.f};
    f32x4 a2s[4];                       // L2 gates acc, lives across barriers

    const float4* xg = (const float4*)x;
    const size_t xrow = (size_t)(rbase + lc) * TT;
    float4 xq = make_float4(0, 0, 0, 0);
    const float4* xp = xg + xrow + 2;   // next prefetch target = x(2)
    if (isL1) xq = xg[xrow + 1];        // x(t+1) at loop entry (t=0)

    // ---------------- prime: L1 -> h1(0); L2 -> zero h2 plane ----------------
    if (isL1) {
        float4 x0 = xg[xrow + 0];
        unsigned u0 = pk2(x0.x, x0.y) & xmask, u1 = pk2(x0.z, x0.w) & xmask;
        uintx4 uv = {u0, u1, 0u, 0u};
        f16x8 xf = __builtin_bit_cast(f16x8, uv);
        f32x4 a[4];
#pragma unroll
        for (int g = 0; g < 4; ++g) a[g] = MFMA16(wx[g], xf, z4);
        float hv[4];
#pragma unroll
        for (int q = 0; q < 4; ++q)
            hv[q] = cellEW(a[0][q], a[1][q], a[2][q], a[3][q], bq[q], c_st[q]);
        uint2 w2 = make_uint2(pk2(hv[0], hv[1]), pk2(hv[2], hv[3]));
        *(uint2*)((char*)h1p[0] + wro) = w2;
    } else {
        h2p[tid] = 0;
        h2p[256 + tid] = 0;
    }
    __syncthreads();

    // ---------------- step body (flags fold at compile time) ----------------
    auto STEP = [&](const unsigned* h1r, unsigned* h1w,
                    bool l1act, bool pref, bool ew2act) {
        f32x4 a1[4];
        // ======== H1: L1 MFMA(gates1) ∥ L2 EW(prev gates2) ========
        if (isL1) {
            if (l1act) {
                const char* pl = (const char*)h1r;
                f16x8 hf0 = *(const f16x8*)(pl + rdo0);
                f16x8 hf1 = *(const f16x8*)(pl + rdo1);
                float4 xn;
                if (pref) { xn = *xp; ++xp; }
                unsigned u0 = pk2(xq.x, xq.y) & xmask, u1 = pk2(xq.z, xq.w) & xmask;
                uintx4 uv = {u0, u1, 0u, 0u};
                f16x8 xf = __builtin_bit_cast(f16x8, uv);
                __builtin_amdgcn_s_setprio(1);
#pragma unroll
                for (int g = 0; g < 4; ++g) {
                    a1[g] = MFMA16(wx[g], xf, z4);
                    a1[g] = MFMA16(wA[g][0], hf0, a1[g]);
                    a1[g] = MFMA16(wA[g][1], hf1, a1[g]);
                }
                __builtin_amdgcn_s_setprio(0);
                if (pref) xq = xn;
            }
        } else {
            if (ew2act) {
                float hv[4];
#pragma unroll
                for (int q = 0; q < 4; ++q)
                    hv[q] = cellEW(a2s[0][q], a2s[1][q], a2s[2][q], a2s[3][q], bq[q], c_st[q]);
                uint2 w2 = make_uint2(pk2(hv[0], hv[1]), pk2(hv[2], hv[3]));
                *(uint2*)((char*)h2p + wro) = w2;
            }
        }
        bar();
        // ======== H2: L1 EW(a1) ∥ L2 MFMA(gates2) ========
        if (isL1) {
            if (l1act) {
                float hv[4];
#pragma unroll
                for (int q = 0; q < 4; ++q)
                    hv[q] = cellEW(a1[0][q], a1[1][q], a1[2][q], a1[3][q], bq[q], c_st[q]);
                uint2 w2 = make_uint2(pk2(hv[0], hv[1]), pk2(hv[2], hv[3]));
                *(uint2*)((char*)h1w + wro) = w2;
            }
        } else {
            const char* pl1 = (const char*)h1r;
            const char* pl2 = (const char*)h2p;
            f16x8 hf0 = *(const f16x8*)(pl1 + rdo0);
            f16x8 hf1 = *(const f16x8*)(pl1 + rdo1);
            f16x8 gf0 = *(const f16x8*)(pl2 + rdo0);
            f16x8 gf1 = *(const f16x8*)(pl2 + rdo1);
            __builtin_amdgcn_s_setprio(1);
#pragma unroll
            for (int g = 0; g < 4; ++g) {
                a2s[g] = MFMA16(wA[g][0], hf0, z4);
                a2s[g] = MFMA16(wA[g][1], hf1, a2s[g]);
                a2s[g] = MFMA16(wB[g][0], gf0, a2s[g]);
                a2s[g] = MFMA16(wB[g][1], gf1, a2s[g]);
            }
            __builtin_amdgcn_s_setprio(0);
        }
        bar();
    };

    // ---------------- main loop ----------------
    // t=0: no EW2 yet
    STEP(h1p[0], h1p[1], true, true, false);
    // t = 1..508, unrolled x2 (planes hardcoded)
    for (int k = 0; k < 254; ++k) {
        STEP(h1p[1], h1p[0], true, true, true);   // odd t
        STEP(h1p[0], h1p[1], true, true, true);   // even t
    }
    // t=509 (prefetches x(511)), t=510 (no prefetch), t=511 (L2 only)
    STEP(h1p[1], h1p[0], true, true,  true);
    STEP(h1p[0], h1p[1], true, false, true);
    STEP(h1p[1], h1p[0], false, false, true);

    // ---------------- epilogue: EW2 on gates2(511) -> sH ----------------
    if (!isL1) {
        float hv[4];
#pragma unroll
        for (int q = 0; q < 4; ++q)
            hv[q] = cellEW(a2s[0][q], a2s[1][q], a2s[2][q], a2s[3][q], bq[q], c_st[q]);
        *(float4*)&sH[lc * 68 + hc0] = make_float4(hv[0], hv[1], hv[2], hv[3]);
    }
    __syncthreads();

    // ---------------- FC head ----------------
    {
        const int r = tid >> 5, mo = tid & 31;
        float s = fc1_b[mo];
#pragma unroll 8
        for (int k = 0; k < 64; ++k) s = fmaf(sH[r * 68 + k], fc1_w[mo * 64 + k], s);
        sY[r * 34 + mo] = fmaxf(s, 0.f);
    }
    __syncthreads();
    if (tid < 32) {
        const int r = tid >> 1, o = tid & 1;
        float s = fc2_b[o];
#pragma unroll 8
        for (int mo = 0; mo < 32; ++mo) s = fmaf(sY[r * 34 + mo], fc2_w[o * 32 + mo], s);
        out[(size_t)(rbase + r) * 2 + o] = fmaxf(s, 0.f);
    }
}

extern "C" void kernel_launch(void* const* d_in, const int* in_sizes, int n_in,
                              void* d_out, int out_size, void* d_ws, size_t ws_size,
                              hipStream_t stream) {
    const float* x     = (const float*)d_in[0];
    const float* w_ih0 = (const float*)d_in[1];
    const float* w_hh0 = (const float*)d_in[2];
    const float* b_ih0 = (const float*)d_in[3];
    const float* b_hh0 = (const float*)d_in[4];
    const float* w_ih1 = (const float*)d_in[5];
    const float* w_hh1 = (const float*)d_in[6];
    const float* b_ih1 = (const float*)d_in[7];
    const float* b_hh1 = (const float*)d_in[8];
    const float* fc1_w = (const float*)d_in[9];
    const float* fc1_b = (const float*)d_in[10];
    const float* fc2_w = (const float*)d_in[11];
    const float* fc2_b = (const float*)d_in[12];
    float* out = (float*)d_out;

    const int nB   = in_sizes[0] / (TT * 4);   // 4096 rows
    const int grid = nB / MM;                  // 256 blocks -> 1/CU

    lstm_v12<<<grid, 512, 0, stream>>>(x, w_ih0, w_hh0, b_ih0, b_hh0,
                                       w_ih1, w_hh1, b_ih1, b_hh1,
                                       fc1_w, fc1_b, fc2_w, fc2_b, out);
}

// Round 14
// 371.264 us; speedup vs baseline: 1.1746x; 1.1746x over previous
//
#include <hip/hip_runtime.h>

#define TT 512
#define MM 16      // batch rows per block; grid 256 = 1 block/CU (min-work shape)

typedef _Float16 f16_t;
typedef f16_t f16x8 __attribute__((ext_vector_type(8)));
typedef float  f32x4 __attribute__((ext_vector_type(4)));
typedef unsigned uintx4 __attribute__((ext_vector_type(4)));

#define MFMA16(A, B, C) __builtin_amdgcn_mfma_f32_16x16x32_f16((A), (B), (C), 0, 0, 0)

__device__ __forceinline__ float fr(float x) { return __builtin_amdgcn_rcpf(x); }

#if __has_builtin(__builtin_amdgcn_exp2f)
__device__ __forceinline__ float ex2(float x) { return __builtin_amdgcn_exp2f(x); }
#define EXS 1.44269504f
#else
__device__ __forceinline__ float ex2(float x) { return __expf(x); }
#define EXS 1.0f
#endif

#if __has_builtin(__builtin_amdgcn_cvt_pkrtz)
__device__ __forceinline__ unsigned pk2(float a, float b) {
    auto p = __builtin_amdgcn_cvt_pkrtz(a, b);   // __fp16 ext_vector(2)
    return __builtin_bit_cast(unsigned, p);
}
#else
__device__ __forceinline__ unsigned pk2(float a, float b) {
    unsigned short ha = __builtin_bit_cast(unsigned short, (f16_t)a);
    unsigned short hb = __builtin_bit_cast(unsigned short, (f16_t)b);
    return (unsigned)ha | ((unsigned)hb << 16);
}
#endif

// barrier: LDS-only wait (everything cross-wave is LDS).
__device__ __forceinline__ void bar() {
    asm volatile("s_waitcnt lgkmcnt(0)" ::: "memory");
    __builtin_amdgcn_s_barrier();
    asm volatile("" ::: "memory");
}

// LSTM cell, 7 trans (5 ex2 + 2 rcp), NaN-safe (identical math to R10/R11):
//   c' = (c*u + oa*(C-1)) * rcp(oa*u);  oa = 1+e^-f^, u = (1+e^-i^)(C+1), C = e^2g^
//   h  = (E-1) * rcp((1+D)(E+1)),  E = 2^min(2*EXS*c', 30)
// Biases pre-folded & scaled: bq = { -EXS*bi, -EXS*bf, 2*EXS*bg, -EXS*bo }.
__device__ __forceinline__ float cellEW(float pi, float pf, float pg, float po,
                                        float4 bq, float& c) {
    float A = ex2(fmaf(pf, -EXS, bq.y));
    float B = ex2(fmaf(pi, -EXS, bq.x));
    float C = ex2(fmaf(pg, 2.f * EXS, bq.z));
    float oa = 1.f + A;
    float u  = (1.f + B) * (C + 1.f);
    float cn = fmaf(c, u, oa * (C - 1.f)) * fr(oa * u);
    c = cn;
    float D = ex2(fmaf(po, -EXS, bq.w));
    float E = ex2(fminf(2.f * EXS * cn, 30.f));
    return (E - 1.f) * fr((1.f + D) * (E + 1.f));
}

__device__ __forceinline__ f16x8 cvt8(const float* p) {
    f16x8 r;
#pragma unroll
    for (int e = 0; e < 8; ++e) r[e] = (f16_t)p[e];
    return r;
}

// SWAPPED-OPERAND MFMA (verified R10/R11):
//   A (arg0) = weight tile:  lane l -> gcol = tile + l%16, k = (l/16)*8+e
//   B (arg1) = h:            lane l -> row  = l%16,        k = (l/16)*8+e
//   D:                       lane l -> row  = l%16, gcol-in-tile = (l/16)*4+q
// h-plane [16 rows][64 hcols] f16, byte(row,hcol) = (row*128 + hcol*2) ^ ((row&7)<<4).
// Wave roles: wv 0..3 = layer 2, wv 4..7 = layer 1 (layer-pipelined, 1 barrier/step).
//
// R14 = R13 with the LDS sizing fixed via DYNAMIC shared memory (R1-proven path):
// xpk needs 16*512*8B = 64 KB (R13 declared 32 KB -> overflow corrupted h planes).
// Dynamic-LDS carve-up (bytes):
//   0      xpk   65536   x pre-packed f16, [t][row] qwords
//   65536  h1p    4096   2 planes
//   69632  h2p    4096   2 planes
//   73728  zq       16   zero qword for lq!=0 lanes
//   73744  sH     4352
//   78096  sY     2176   -> total 80272

#define SMEM_BYTES 80272

__global__ __launch_bounds__(512, 2) void lstm_v14(
    const float* __restrict__ x,
    const float* __restrict__ w_ih0, const float* __restrict__ w_hh0,
    const float* __restrict__ b_ih0, const float* __restrict__ b_hh0,
    const float* __restrict__ w_ih1, const float* __restrict__ w_hh1,
    const float* __restrict__ b_ih1, const float* __restrict__ b_hh1,
    const float* __restrict__ fc1_w, const float* __restrict__ fc1_b,
    const float* __restrict__ fc2_w, const float* __restrict__ fc2_b,
    float* __restrict__ out)
{
    extern __shared__ __align__(16) char sm[];
    unsigned* xpk = (unsigned*)(sm);                         // 64 KB
    unsigned (*h1p)[512] = (unsigned(*)[512])(sm + 65536);   // [2][512]
    unsigned (*h2p)[512] = (unsigned(*)[512])(sm + 69632);   // [2][512]
    unsigned* zq = (unsigned*)(sm + 73728);
    float* sH = (float*)(sm + 73744);
    float* sY = (float*)(sm + 78096);

    const int tid = threadIdx.x;
    const int l   = tid & 63;
    const int wv  = tid >> 6;
    const int rbase = blockIdx.x * MM;

    const int lc = l & 15;
    const int lq = l >> 4;
    const bool isL1 = (wv >= 4);
    const int wsub = wv & 3;
    const int hc0  = wsub * 16 + lq * 4;
    const int swz  = (lc & 7) << 4;

    const int rdo0 = (lc * 128 + 0 * 64 + lq * 16) ^ swz;
    const int rdo1 = (lc * 128 + 1 * 64 + lq * 16) ^ swz;
    const int wro  = (lc * 128 + hc0 * 2) ^ swz;

    // ---------------- prologue A: pre-pack x to f16 in LDS ----------------
    {
        const float4* xsrc = (const float4*)x;
        for (int j = tid; j < 16 * 512; j += 512) {
            const int row = j >> 9;           // 0..15  (iter index)
            const int tt  = j & 511;          // = tid  -> coalesced global reads
            float4 v = xsrc[(size_t)(rbase + row) * TT + tt];
            uint2 w = make_uint2(pk2(v.x, v.y), pk2(v.z, v.w));
            *(uint2*)((char*)xpk + (size_t)(tt * 16 + row) * 8) = w;
        }
        if (tid == 0) { zq[0] = 0; zq[1] = 0; zq[2] = 0; zq[3] = 0; }
    }
    // per-lane x pointers (L1 only uses them)
    const char* xbp  = (lq == 0) ? ((const char*)xpk + (16 + lc) * 8) : (const char*)zq;
    const char* x0p  = (lq == 0) ? ((const char*)xpk + lc * 8)        : (const char*)zq;
    const int   xstr = (lq == 0) ? 128 : 0;

    // ---------------- prologue B: weight A-fragments -> registers ----------------
    f16x8 wA[4][2];   // L1: w_hh0 ; L2: w_ih1
    f16x8 wB[4][2];   // L2 only: w_hh1
    f16x8 wx[4];      // L1 only: w_ih0 (k=0..3)
    float4 bq[4];
#pragma unroll
    for (int g = 0; g < 4; ++g) {
        const int grow = (g * 64 + wsub * 16 + lc) * 64 + lq * 8;
        if (isL1) {
            wA[g][0] = cvt8(w_hh0 + grow);
            wA[g][1] = cvt8(w_hh0 + grow + 32);
            const int ga = (g * 64 + wsub * 16 + lc) * 4;
#pragma unroll
            for (int e = 0; e < 8; ++e)
                wx[g][e] = (e < 4 && lq == 0) ? (f16_t)w_ih0[ga + e] : (f16_t)0.f;
        } else {
            wA[g][0] = cvt8(w_ih1 + grow);
            wA[g][1] = cvt8(w_ih1 + grow + 32);
            wB[g][0] = cvt8(w_hh1 + grow);
            wB[g][1] = cvt8(w_hh1 + grow + 32);
        }
    }
#pragma unroll
    for (int q = 0; q < 4; ++q) {
        const int hc = hc0 + q;
        float b[4];
#pragma unroll
        for (int g = 0; g < 4; ++g) {
            const int ga = g * 64 + hc;
            b[g] = isL1 ? (b_ih0[ga] + b_hh0[ga]) : (b_ih1[ga] + b_hh1[ga]);
        }
        bq[q] = make_float4(-EXS * b[0], -EXS * b[1], 2.f * EXS * b[2], -EXS * b[3]);
    }

    float c_st[4] = {0.f, 0.f, 0.f, 0.f};
    const f32x4 z4 = {0.f, 0.f, 0.f, 0.f};

    __syncthreads();   // xpk + zq ready

    // ---------------- prime: L1 -> h1(0); L2 -> zero h2 plane 0 ----------------
    if (isL1) {
        uint2 x0 = *(const uint2*)x0p;
        uintx4 uv = {x0.x, x0.y, 0u, 0u};
        f16x8 xf = __builtin_bit_cast(f16x8, uv);
        f32x4 a[4];
#pragma unroll
        for (int g = 0; g < 4; ++g) a[g] = MFMA16(wx[g], xf, z4);
        float hv[4];
#pragma unroll
        for (int q = 0; q < 4; ++q)
            hv[q] = cellEW(a[0][q], a[1][q], a[2][q], a[3][q], bq[q], c_st[q]);
        uint2 w2 = make_uint2(pk2(hv[0], hv[1]), pk2(hv[2], hv[3]));
        *(uint2*)((char*)h1p[0] + wro) = w2;
    } else {
        h2p[0][tid] = 0;
        h2p[0][256 + tid] = 0;
    }
    __syncthreads();

    // asymmetric priority: L2 leads for the whole recurrence
    if (!isL1) __builtin_amdgcn_s_setprio(1);

    // ---------------- step body (flags fold at compile time) ----------------
    auto STEP = [&](const unsigned* h1r, unsigned* h1w,
                    const unsigned* h2r, unsigned* h2w,
                    bool l1act, bool pref, bool lastStore) {
        if (isL1) {
            if (l1act) {
                const char* pl = (const char*)h1r;
                f16x8 hf0 = *(const f16x8*)(pl + rdo0);
                f16x8 hf1 = *(const f16x8*)(pl + rdo1);
                uint2 xu = *(const uint2*)xbp;
                if (pref) xbp += xstr;
                uintx4 uv = {xu.x, xu.y, 0u, 0u};
                f16x8 xf = __builtin_bit_cast(f16x8, uv);

                f32x4 a[4];
#pragma unroll
                for (int g = 0; g < 4; ++g) {
                    a[g] = MFMA16(wx[g], xf, z4);
                    a[g] = MFMA16(wA[g][0], hf0, a[g]);
                    a[g] = MFMA16(wA[g][1], hf1, a[g]);
                }
                float hv[4];
#pragma unroll
                for (int q = 0; q < 4; ++q)
                    hv[q] = cellEW(a[0][q], a[1][q], a[2][q], a[3][q], bq[q], c_st[q]);
                uint2 w2 = make_uint2(pk2(hv[0], hv[1]), pk2(hv[2], hv[3]));
                *(uint2*)((char*)h1w + wro) = w2;
            }
        } else {
            const char* pl1 = (const char*)h1r;
            const char* pl2 = (const char*)h2r;
            f16x8 hf0 = *(const f16x8*)(pl1 + rdo0);
            f16x8 hf1 = *(const f16x8*)(pl1 + rdo1);
            f16x8 gf0 = *(const f16x8*)(pl2 + rdo0);
            f16x8 gf1 = *(const f16x8*)(pl2 + rdo1);

            f32x4 a[4];
#pragma unroll
            for (int g = 0; g < 4; ++g) {
                a[g] = MFMA16(wA[g][0], hf0, z4);
                a[g] = MFMA16(wA[g][1], hf1, a[g]);
                a[g] = MFMA16(wB[g][0], gf0, a[g]);
                a[g] = MFMA16(wB[g][1], gf1, a[g]);
            }
            float hv[4];
#pragma unroll
            for (int q = 0; q < 4; ++q)
                hv[q] = cellEW(a[0][q], a[1][q], a[2][q], a[3][q], bq[q], c_st[q]);
            uint2 w2 = make_uint2(pk2(hv[0], hv[1]), pk2(hv[2], hv[3]));
            *(uint2*)((char*)h2w + wro) = w2;
            if (lastStore)
                *(float4*)&sH[lc * 68 + hc0] = make_float4(hv[0], hv[1], hv[2], hv[3]);
        }
        bar();
    };

    // ---------------- main loop: t = 0..509, unrolled x2, no conditionals ----------------
    for (int it = 0; it < 255; ++it) {
        STEP(h1p[0], h1p[1], h2p[0], h2p[1], true, true, false);   // even t
        STEP(h1p[1], h1p[0], h2p[1], h2p[0], true, true, false);   // odd t
    }
    // t = 510: L1 computes gates1(511) (reads x(511), no pointer bump); L2 -> h2(510)
    STEP(h1p[0], h1p[1], h2p[0], h2p[1], true, false, false);
    // t = 511: L2 only -> h2(511) + sH
    STEP(h1p[1], h1p[0], h2p[1], h2p[0], false, false, true);

    if (!isL1) __builtin_amdgcn_s_setprio(0);

    // ---------------- FC head ----------------
    {
        const int r = tid >> 5, mo = tid & 31;
        float s = fc1_b[mo];
#pragma unroll 8
        for (int k = 0; k < 64; ++k) s = fmaf(sH[r * 68 + k], fc1_w[mo * 64 + k], s);
        sY[r * 34 + mo] = fmaxf(s, 0.f);
    }
    __syncthreads();
    if (tid < 32) {
        const int r = tid >> 1, o = tid & 1;
        float s = fc2_b[o];
#pragma unroll 8
        for (int mo = 0; mo < 32; ++mo) s = fmaf(sY[r * 34 + mo], fc2_w[o * 32 + mo], s);
        out[(size_t)(rbase + r) * 2 + o] = fmaxf(s, 0.f);
    }
}

extern "C" void kernel_launch(void* const* d_in, const int* in_sizes, int n_in,
                              void* d_out, int out_size, void* d_ws, size_t ws_size,
                              hipStream_t stream) {
    const float* x     = (const float*)d_in[0];
    const float* w_ih0 = (const float*)d_in[1];
    const float* w_hh0 = (const float*)d_in[2];
    const float* b_ih0 = (const float*)d_in[3];
    const float* b_hh0 = (const float*)d_in[4];
    const float* w_ih1 = (const float*)d_in[5];
    const float* w_hh1 = (const float*)d_in[6];
    const float* b_ih1 = (const float*)d_in[7];
    const float* b_hh1 = (const float*)d_in[8];
    const float* fc1_w = (const float*)d_in[9];
    const float* fc1_b = (const float*)d_in[10];
    const float* fc2_w = (const float*)d_in[11];
    const float* fc2_b = (const float*)d_in[12];
    float* out = (float*)d_out;

    const int nB   = in_sizes[0] / (TT * 4);   // 4096 rows
    const int grid = nB / MM;                  // 256 blocks -> 1/CU

    hipFuncSetAttribute(reinterpret_cast<const void*>(lstm_v14),
                        hipFuncAttributeMaxDynamicSharedMemorySize, SMEM_BYTES);

    lstm_v14<<<grid, 512, SMEM_BYTES, stream>>>(x, w_ih0, w_hh0, b_ih0, b_hh0,
                                                w_ih1, w_hh1, b_ih1, b_hh1,
                                                fc1_w, fc1_b, fc2_w, fc2_b, out);
}